// Round 1
// baseline (969.118 us; speedup 1.0000x reference)
//
#include <hip/hip_runtime.h>
#include <hip/hip_bf16.h>
#include <stdint.h>

// ---------------------------------------------------------------------------
// HandNet: 3 encoder GNN blocks (chain graphs) -> trans GEMM (tanh) ->
// 3 decoder GNN blocks -> angles -> Rodrigues FK.
// Graph topology is a fixed chain: edge j connects node j -> node j+1, so
// segment_sum == "node k receives one message from edge k-1" (no atomics).
// ---------------------------------------------------------------------------

#define ZSIZE 18874368   // 16384*1152
#define AHALF 147456     // B*Jt
#define PHALF 442368     // AHALF*3

using f32x4  = __attribute__((ext_vector_type(4))) float;
using bf16x8 = __attribute__((ext_vector_type(8))) short;

__device__ __forceinline__ float tanh_fast(float x) {
    x = fminf(40.f, fmaxf(-40.f, x));
    float e = __expf(2.f * x);
    return (e - 1.f) / (e + 1.f);
}
__device__ __forceinline__ float lrelu(float x) { return x > 0.f ? x : 0.01f * x; }

// ---------------------------------------------------------------------------
// Wt prep: trans_w (1088 x 1152 f32) -> Wt (1152 x 3264 bf16), where
// Wt[n][k]       = hi(W[k][n])        k in [0,1088)
// Wt[n][1088+k]  = hi(W[k][n])
// Wt[n][2176+k]  = lo(W[k][n])
// ---------------------------------------------------------------------------
__global__ __launch_bounds__(256) void prep_wt(const float* __restrict__ W,
                                               __hip_bfloat16* __restrict__ Wt) {
    __shared__ float t[32][33];
    const int k0 = blockIdx.x * 32;   // 1088 = 34*32
    const int n0 = blockIdx.y * 32;   // 1152 = 36*32
    const int tx = threadIdx.x, ty = threadIdx.y;
    for (int i = ty; i < 32; i += 8)
        t[i][tx] = W[(size_t)(k0 + i) * 1152 + n0 + tx];
    __syncthreads();
    for (int i = ty; i < 32; i += 8) {
        const int n = n0 + i, k = k0 + tx;
        float v = t[tx][i];
        __hip_bfloat16 hi = __float2bfloat16(v);
        __hip_bfloat16 lo = __float2bfloat16(v - __bfloat162float(hi));
        __hip_bfloat16* row = Wt + (size_t)n * 3264;
        row[k] = hi; row[1088 + k] = hi; row[2176 + k] = lo;
    }
}

// ---------------------------------------------------------------------------
// Fused encoder: enc1 -> enc2 -> enc3 per graph (17 nodes), 4 graphs/block.
// Writes split-bf16 A' (16384 x 3264): [hi | lo | hi].
// ---------------------------------------------------------------------------
#define EGPB 4
__global__ __launch_bounds__(256) void enc_kernel(
    const float* __restrict__ lx,  const float* __restrict__ rx,
    const float* __restrict__ lea, const float* __restrict__ rea,
    const float* __restrict__ w1l, const float* __restrict__ b1l,
    const float* __restrict__ w1u, const float* __restrict__ b1u,
    const float* __restrict__ w2l, const float* __restrict__ b2l,
    const float* __restrict__ w2u, const float* __restrict__ b2u,
    const float* __restrict__ w3l, const float* __restrict__ b3l,
    const float* __restrict__ w3u, const float* __restrict__ b3u,
    __hip_bfloat16* __restrict__ Ae)
{
    __shared__ float s_w1l[144], s_b1l[16], s_w1u[48],   s_b1u[16];
    __shared__ float s_w2l[1120], s_b2l[32], s_w2u[512], s_b2u[32];
    __shared__ float s_w3l[4288], s_b3l[64], s_w3u[2048], s_b3u[64];
    __shared__ float sx[EGPB][17][3], sea_[EGPB][16][3];
    __shared__ float sh1[EGPB][17][16], sh2[EGPB][17][32];

    const int tid = threadIdx.x;
    for (int i = tid; i < 144;  i += 256) s_w1l[i] = w1l[i];
    for (int i = tid; i < 48;   i += 256) s_w1u[i] = w1u[i];
    for (int i = tid; i < 16;   i += 256) { s_b1l[i] = b1l[i]; s_b1u[i] = b1u[i]; }
    for (int i = tid; i < 1120; i += 256) s_w2l[i] = w2l[i];
    for (int i = tid; i < 512;  i += 256) s_w2u[i] = w2u[i];
    for (int i = tid; i < 32;   i += 256) { s_b2l[i] = b2l[i]; s_b2u[i] = b2u[i]; }
    for (int i = tid; i < 4288; i += 256) s_w3l[i] = w3l[i];
    for (int i = tid; i < 2048; i += 256) s_w3u[i] = w3u[i];
    for (int i = tid; i < 64;   i += 256) { s_b3l[i] = b3l[i]; s_b3u[i] = b3u[i]; }

    const int grp = tid >> 6, lane = tid & 63;
    const int g2 = blockIdx.x * EGPB + grp;      // 0..16383
    const float* xsrc  = (g2 < 8192) ? (lx  + (size_t)g2 * 51) : (rx  + (size_t)(g2 - 8192) * 51);
    const float* easrc = (g2 < 8192) ? (lea + (size_t)g2 * 48) : (rea + (size_t)(g2 - 8192) * 48);
    if (lane < 51) ((float*)sx[grp])[lane]   = xsrc[lane];
    if (lane < 48) ((float*)sea_[grp])[lane] = easrc[lane];
    __syncthreads();

    // ---- enc1: 17x16 outputs ----
    for (int o = lane; o < 272; o += 64) {
        const int nl = o >> 4, f = o & 15;
        const float* xn = sx[grp][nl];
        float acc = s_b1u[f];
        #pragma unroll
        for (int c = 0; c < 3; c++) acc += xn[c] * s_w1u[c * 16 + f];
        if (nl > 0) {
            const float* xp = sx[grp][nl - 1];
            const float* e  = sea_[grp][nl - 1];
            float m = s_b1l[f];
            #pragma unroll
            for (int c = 0; c < 3; c++) m += xn[c] * s_w1l[c * 16 + f];
            #pragma unroll
            for (int c = 0; c < 3; c++) m += xp[c] * s_w1l[(3 + c) * 16 + f];
            #pragma unroll
            for (int c = 0; c < 3; c++) m += e[c]  * s_w1l[(6 + c) * 16 + f];
            acc += lrelu(m);
        }
        sh1[grp][nl][f] = acc;
    }
    __syncthreads();

    // ---- enc2: 17x32 outputs ----
    for (int o = lane; o < 544; o += 64) {
        const int nl = o >> 5, f = o & 31;
        const float* hn = sh1[grp][nl];
        float acc = s_b2u[f];
        #pragma unroll
        for (int c = 0; c < 16; c++) acc += hn[c] * s_w2u[c * 32 + f];
        if (nl > 0) {
            const float* hp = sh1[grp][nl - 1];
            const float* e  = sea_[grp][nl - 1];
            float m = s_b2l[f];
            #pragma unroll
            for (int c = 0; c < 16; c++) m += hn[c] * s_w2l[c * 32 + f];
            #pragma unroll
            for (int c = 0; c < 16; c++) m += hp[c] * s_w2l[(16 + c) * 32 + f];
            #pragma unroll
            for (int c = 0; c < 3;  c++) m += e[c]  * s_w2l[(32 + c) * 32 + f];
            acc += lrelu(m);
        }
        sh2[grp][nl][f] = acc;
    }
    __syncthreads();

    // ---- enc3: 17x64 outputs -> split bf16 into A' row g2 ----
    __hip_bfloat16* arow = Ae + (size_t)g2 * 3264;
    for (int o = lane; o < 1088; o += 64) {
        const int nl = o >> 6, f = o & 63;
        const float* hn = sh2[grp][nl];
        float acc = s_b3u[f];
        #pragma unroll
        for (int c = 0; c < 32; c++) acc += hn[c] * s_w3u[c * 64 + f];
        if (nl > 0) {
            const float* hp = sh2[grp][nl - 1];
            const float* e  = sea_[grp][nl - 1];
            float m = s_b3l[f];
            #pragma unroll
            for (int c = 0; c < 32; c++) m += hn[c] * s_w3l[c * 64 + f];
            #pragma unroll
            for (int c = 0; c < 32; c++) m += hp[c] * s_w3l[(32 + c) * 64 + f];
            #pragma unroll
            for (int c = 0; c < 3;  c++) m += e[c]  * s_w3l[(64 + c) * 64 + f];
            acc += lrelu(m);
        }
        __hip_bfloat16 hi = __float2bfloat16(acc);
        __hip_bfloat16 lo = __float2bfloat16(acc - __bfloat162float(hi));
        arow[o] = hi; arow[1088 + o] = lo; arow[2176 + o] = hi;
    }
}

// ---------------------------------------------------------------------------
// trans GEMM: Z = tanh(A'(16384x3264) @ Wt^T + b), split-bf16 exact to ~2^-17.
// 128x128 tile, BK=32, 4 waves each 64x64 (4x4 mfma_f32_16x16x32_bf16).
// LDS rows padded to 40 shorts (80B) to spread banks for ds_read_b128.
// ---------------------------------------------------------------------------
__global__ __launch_bounds__(256) void trans_gemm(
    const short* __restrict__ A, const short* __restrict__ Bt,
    const float* __restrict__ bias, float* __restrict__ Z)
{
    __shared__ __align__(16) short As[128 * 40];
    __shared__ __align__(16) short Bs[128 * 40];
    const int tid = threadIdx.x;
    const int bm = blockIdx.x * 128, bn = blockIdx.y * 128;
    const int lane = tid & 63, wave = tid >> 6;
    const int wr = wave >> 1, wc = wave & 1;
    const int quad = lane >> 4, l16 = lane & 15;

    // staging: 512 chunks of 16B per tile, 2 per thread
    const int c0 = tid, c1 = tid + 256;
    const int r0 = c0 >> 2, kc0 = c0 & 3;
    const int r1 = c1 >> 2, kc1 = c1 & 3;
    const size_t gA0 = (size_t)(bm + r0) * 3264 + kc0 * 8;
    const size_t gA1 = (size_t)(bm + r1) * 3264 + kc1 * 8;
    const size_t gB0 = (size_t)(bn + r0) * 3264 + kc0 * 8;
    const size_t gB1 = (size_t)(bn + r1) * 3264 + kc1 * 8;
    const int lo0 = r0 * 40 + kc0 * 8, lo1 = r1 * 40 + kc1 * 8;

    f32x4 acc[4][4];
    #pragma unroll
    for (int i = 0; i < 4; i++)
        #pragma unroll
        for (int j = 0; j < 4; j++)
            #pragma unroll
            for (int r = 0; r < 4; r++) acc[i][j][r] = 0.f;

    for (int k0 = 0; k0 < 3264; k0 += 32) {
        uint4 a0 = *(const uint4*)(A + gA0 + k0);
        uint4 a1 = *(const uint4*)(A + gA1 + k0);
        uint4 b0 = *(const uint4*)(Bt + gB0 + k0);
        uint4 b1 = *(const uint4*)(Bt + gB1 + k0);
        *(uint4*)&As[lo0] = a0; *(uint4*)&As[lo1] = a1;
        *(uint4*)&Bs[lo0] = b0; *(uint4*)&Bs[lo1] = b1;
        __syncthreads();
        bf16x8 af[4], bfr[4];
        #pragma unroll
        for (int mi = 0; mi < 4; mi++)
            af[mi] = *(const bf16x8*)&As[(wr * 64 + mi * 16 + l16) * 40 + quad * 8];
        #pragma unroll
        for (int ni = 0; ni < 4; ni++)
            bfr[ni] = *(const bf16x8*)&Bs[(wc * 64 + ni * 16 + l16) * 40 + quad * 8];
        #pragma unroll
        for (int mi = 0; mi < 4; mi++)
            #pragma unroll
            for (int ni = 0; ni < 4; ni++)
                acc[mi][ni] = __builtin_amdgcn_mfma_f32_16x16x32_bf16(
                    af[mi], bfr[ni], acc[mi][ni], 0, 0, 0);
        __syncthreads();
    }

    // epilogue: bias + tanh, D layout col=lane&15, row=quad*4+r
    #pragma unroll
    for (int mi = 0; mi < 4; mi++) {
        #pragma unroll
        for (int ni = 0; ni < 4; ni++) {
            const int n = bn + wc * 64 + ni * 16 + l16;
            const float bv = bias[n];
            #pragma unroll
            for (int r = 0; r < 4; r++) {
                const int m = bm + wr * 64 + mi * 16 + quad * 4 + r;
                Z[(size_t)m * 1152 + n] = tanh_fast(acc[mi][ni][r] + bv);
            }
        }
    }
}

// ---------------------------------------------------------------------------
// Fused decoder + FK: dec1 -> dec2 -> dec3 -> angles -> FK, 2 graphs/block
// (128 threads per graph, 18 nodes each).
// ---------------------------------------------------------------------------
#define DGPB 2
__global__ __launch_bounds__(256) void dec_kernel(
    const float* __restrict__ Zc,  const float* __restrict__ tea,
    const float* __restrict__ lo_, const float* __restrict__ up_,
    const float* __restrict__ off_, const int* __restrict__ par_,
    const float* __restrict__ ax_,
    const float* __restrict__ w1l, const float* __restrict__ b1l,
    const float* __restrict__ w1u, const float* __restrict__ b1u,
    const float* __restrict__ w2l, const float* __restrict__ b2l,
    const float* __restrict__ w2u, const float* __restrict__ b2u,
    const float* __restrict__ w3l, const float* __restrict__ b3l,
    const float* __restrict__ w3u, const float* __restrict__ b3u,
    float* __restrict__ out)
{
    __shared__ float s_w1l[4416], s_w1u[2112], s_b1l[32], s_b1u[32];
    __shared__ float s_w2l[1120], s_w2u[512],  s_b2l[16], s_b2u[16];
    __shared__ float s_w3l[38],   s_w3u[16];
    __shared__ float s_b3l1, s_b3u1;
    __shared__ float sxd[DGPB][18][66];
    __shared__ float sea_[DGPB][17][6];
    __shared__ float sh1[DGPB][18][32];
    __shared__ float sh2[DGPB][18][16];
    __shared__ float sang[DGPB][18];

    const int tid = threadIdx.x;
    for (int i = tid; i < 4416; i += 256) s_w1l[i] = w1l[i];
    for (int i = tid; i < 2112; i += 256) s_w1u[i] = w1u[i];
    for (int i = tid; i < 32;   i += 256) { s_b1l[i] = b1l[i]; s_b1u[i] = b1u[i]; }
    for (int i = tid; i < 1120; i += 256) s_w2l[i] = w2l[i];
    for (int i = tid; i < 512;  i += 256) s_w2u[i] = w2u[i];
    for (int i = tid; i < 16;   i += 256) { s_b2l[i] = b2l[i]; s_b2u[i] = b2u[i]; s_w3u[i] = w3u[i]; }
    for (int i = tid; i < 38;   i += 256) s_w3l[i] = w3l[i];
    if (tid == 0) { s_b3l1 = b3l[0]; s_b3u1 = b3u[0]; }

    const int grp = tid >> 7, lane = tid & 127;
    const int g2 = blockIdx.x * DGPB + grp;     // 0..16383
    const int gb = (g2 & 8191) * 18;            // index into per-hand arrays

    // xd = [z(64) | lo | up]
    for (int i = lane; i < 1152; i += 128)
        sxd[grp][i >> 6][i & 63] = Zc[(size_t)g2 * 1152 + i];
    if (lane < 18) {
        sxd[grp][lane][64] = lo_[gb + lane];
        sxd[grp][lane][65] = up_[gb + lane];
    }
    if (lane < 102) ((float*)sea_[grp])[lane] = tea[(size_t)(g2 & 8191) * 102 + lane];
    __syncthreads();

    // ---- dec1: 18x32 ----
    for (int o = lane; o < 576; o += 128) {
        const int nl = o >> 5, f = o & 31;
        const float* xn = sxd[grp][nl];
        float acc = s_b1u[f];
        #pragma unroll
        for (int c = 0; c < 66; c++) acc += xn[c] * s_w1u[c * 32 + f];
        if (nl > 0) {
            const float* xp = sxd[grp][nl - 1];
            const float* e  = sea_[grp][nl - 1];
            float m = s_b1l[f];
            #pragma unroll
            for (int c = 0; c < 66; c++) m += xn[c] * s_w1l[c * 32 + f];
            #pragma unroll
            for (int c = 0; c < 66; c++) m += xp[c] * s_w1l[(66 + c) * 32 + f];
            #pragma unroll
            for (int c = 0; c < 6;  c++) m += e[c]  * s_w1l[(132 + c) * 32 + f];
            acc += lrelu(m);
        }
        sh1[grp][nl][f] = acc;
    }
    __syncthreads();

    // ---- dec2: 18x16 ----
    for (int o = lane; o < 288; o += 128) {
        const int nl = o >> 4, f = o & 15;
        const float* hn = sh1[grp][nl];
        float acc = s_b2u[f];
        #pragma unroll
        for (int c = 0; c < 32; c++) acc += hn[c] * s_w2u[c * 16 + f];
        if (nl > 0) {
            const float* hp = sh1[grp][nl - 1];
            const float* e  = sea_[grp][nl - 1];
            float m = s_b2l[f];
            #pragma unroll
            for (int c = 0; c < 32; c++) m += hn[c] * s_w2l[c * 16 + f];
            #pragma unroll
            for (int c = 0; c < 32; c++) m += hp[c] * s_w2l[(32 + c) * 16 + f];
            #pragma unroll
            for (int c = 0; c < 6;  c++) m += e[c]  * s_w2l[(64 + c) * 16 + f];
            acc += lrelu(m);
        }
        sh2[grp][nl][f] = acc;
    }
    __syncthreads();

    // ---- dec3 (18x1) + tanh + angle ----
    if (lane < 18) {
        const int nl = lane;
        const float* hn = sh2[grp][nl];
        float acc = s_b3u1;
        #pragma unroll
        for (int c = 0; c < 16; c++) acc += hn[c] * s_w3u[c];
        if (nl > 0) {
            const float* hp = sh2[grp][nl - 1];
            const float* e  = sea_[grp][nl - 1];
            float m = s_b3l1;
            #pragma unroll
            for (int c = 0; c < 16; c++) m += hn[c] * s_w3l[c];
            #pragma unroll
            for (int c = 0; c < 16; c++) m += hp[c] * s_w3l[16 + c];
            #pragma unroll
            for (int c = 0; c < 6;  c++) m += e[c]  * s_w3l[32 + c];
            acc += lrelu(m);
        }
        const float hd = tanh_fast(acc);
        const float lo = sxd[grp][nl][64], up = sxd[grp][nl][65];
        const float ang = lo + (up - lo) * (hd + 1.f) * 0.5f;
        sang[grp][nl] = ang;
        const size_t abase = (g2 < 8192) ? (size_t)ZSIZE + (size_t)g2 * 18
                                         : (size_t)ZSIZE + AHALF + PHALF + (size_t)(g2 - 8192) * 18;
        out[abase + nl] = ang;
    }
    __syncthreads();

    // ---- FK: sequential 18-joint chain, one thread per graph ----
    if (lane == 0) {
        const size_t pbase = (g2 < 8192)
            ? (size_t)ZSIZE + AHALF + (size_t)g2 * 54
            : (size_t)ZSIZE + AHALF + PHALF + AHALF + (size_t)(g2 - 8192) * 54;
        float R[9], p[3];
        for (int j = 0; j < 18; j++) {
            const int m = gb + j;
            const float a0 = ax_[m * 3], a1 = ax_[m * 3 + 1], a2 = ax_[m * 3 + 2];
            const float o0 = off_[m * 3], o1 = off_[m * 3 + 1], o2 = off_[m * 3 + 2];
            const float ang = sang[grp][j];
            float s, c;
            __sincosf(ang, &s, &c);
            const float omc = 1.f - c;
            const float n2 = a0 * a0 + a1 * a1 + a2 * a2;
            // R = I + s*K + (1-c)*K^2, K^2 = a a^T - |a|^2 I (exact identity)
            float Rl[9];
            Rl[0] = 1.f + omc * (a0 * a0 - n2);
            Rl[1] = -s * a2 + omc * a0 * a1;
            Rl[2] =  s * a1 + omc * a0 * a2;
            Rl[3] =  s * a2 + omc * a1 * a0;
            Rl[4] = 1.f + omc * (a1 * a1 - n2);
            Rl[5] = -s * a0 + omc * a1 * a2;
            Rl[6] = -s * a1 + omc * a2 * a0;
            Rl[7] =  s * a0 + omc * a2 * a1;
            Rl[8] = 1.f + omc * (a2 * a2 - n2);
            if (par_[m] < 0) {
                #pragma unroll
                for (int q = 0; q < 9; q++) R[q] = Rl[q];
                p[0] = o0; p[1] = o1; p[2] = o2;
            } else {
                float Rn[9];
                #pragma unroll
                for (int r = 0; r < 3; r++) {
                    Rn[r * 3 + 0] = R[r * 3] * Rl[0] + R[r * 3 + 1] * Rl[3] + R[r * 3 + 2] * Rl[6];
                    Rn[r * 3 + 1] = R[r * 3] * Rl[1] + R[r * 3 + 1] * Rl[4] + R[r * 3 + 2] * Rl[7];
                    Rn[r * 3 + 2] = R[r * 3] * Rl[2] + R[r * 3 + 1] * Rl[5] + R[r * 3 + 2] * Rl[8];
                }
                const float q0 = p[0] + R[0] * o0 + R[1] * o1 + R[2] * o2;
                const float q1 = p[1] + R[3] * o0 + R[4] * o1 + R[5] * o2;
                const float q2 = p[2] + R[6] * o0 + R[7] * o1 + R[8] * o2;
                #pragma unroll
                for (int q = 0; q < 9; q++) R[q] = Rn[q];
                p[0] = q0; p[1] = q1; p[2] = q2;
            }
            out[pbase + j * 3 + 0] = p[0];
            out[pbase + j * 3 + 1] = p[1];
            out[pbase + j * 3 + 2] = p[2];
        }
    }
}

// ---------------------------------------------------------------------------
extern "C" void kernel_launch(void* const* d_in, const int* in_sizes, int n_in,
                              void* d_out, int out_size, void* d_ws, size_t ws_size,
                              hipStream_t stream)
{
    // Input indices follow setup_inputs() dict order; disambiguate trans_w
    // position defensively (dict order: trans after dec3; sig order: before dec1).
    int i_tw, i_tb, i_d1, i_d2, i_d3;
    if (n_in > 27 && in_sizes[26] == 1088 * 1152) {
        i_tw = 26; i_tb = 27; i_d1 = 28; i_d2 = 32; i_d3 = 36;
    } else {
        i_d1 = 26; i_d2 = 30; i_d3 = 34; i_tw = 38; i_tb = 39;
    }
    auto fp = [&](int i) { return (const float*)d_in[i]; };

    __hip_bfloat16* Ae = (__hip_bfloat16*)d_ws;                       // 16384x3264 bf16
    __hip_bfloat16* Wt = (__hip_bfloat16*)((char*)d_ws + 106954752);  // 1152x3264 bf16

    prep_wt<<<dim3(34, 36), dim3(32, 8), 0, stream>>>(fp(i_tw), Wt);

    enc_kernel<<<4096, 256, 0, stream>>>(
        fp(0), fp(1), fp(4), fp(5),
        fp(14), fp(15), fp(16), fp(17),
        fp(18), fp(19), fp(20), fp(21),
        fp(22), fp(23), fp(24), fp(25), Ae);

    trans_gemm<<<dim3(128, 9), 256, 0, stream>>>(
        (const short*)Ae, (const short*)Wt, fp(i_tb), (float*)d_out);

    dec_kernel<<<8192, 256, 0, stream>>>(
        (const float*)d_out, fp(7), fp(8), fp(9), fp(10),
        (const int*)d_in[11], fp(12),
        fp(i_d1), fp(i_d1 + 1), fp(i_d1 + 2), fp(i_d1 + 3),
        fp(i_d2), fp(i_d2 + 1), fp(i_d2 + 2), fp(i_d2 + 3),
        fp(i_d3), fp(i_d3 + 1), fp(i_d3 + 2), fp(i_d3 + 3),
        (float*)d_out);
}

// Round 2
// 571.491 us; speedup vs baseline: 1.6958x; 1.6958x over previous
//
#include <hip/hip_runtime.h>
#include <hip/hip_bf16.h>
#include <stdint.h>

// ---------------------------------------------------------------------------
// HandNet: 3 encoder GNN blocks (chain graphs) -> trans GEMM fp16 (tanh) ->
// 3 decoder GNN blocks -> angles -> Rodrigues FK.
// Chain topology: node k's only incoming message is from edge k-1 (src k-1).
// R2: register-blocked GNN layers (weights hoisted, independent accum chains),
//     fp16 single-term trans GEMM, global_load_lds w/ XOR-swizzled LDS.
// ---------------------------------------------------------------------------

#define ZSIZE 18874368   // 16384*1152  (z output)
#define AHALF 147456     // 8192*18     (ang half)
#define PHALF 442368     // AHALF*3     (pos half)

using f32x4 = __attribute__((ext_vector_type(4))) float;
using f16x8 = __attribute__((ext_vector_type(8))) _Float16;

__device__ __forceinline__ float tanh_fast(float x) {
    x = fminf(40.f, fmaxf(-40.f, x));
    float e = __expf(2.f * x);
    return (e - 1.f) / (e + 1.f);
}
__device__ __forceinline__ float lrelu(float x) { return x > 0.f ? x : 0.01f * x; }

__device__ __forceinline__ void gload_lds16(const void* g, void* l) {
    __builtin_amdgcn_global_load_lds(
        (__attribute__((address_space(1))) unsigned int*)g,
        (__attribute__((address_space(3))) unsigned int*)l, 16, 0, 0);
}

// ---------------------------------------------------------------------------
// Wt prep: trans_w (1088 x 1152 f32) -> Wt (1152 x 1088 f16) transpose.
// ---------------------------------------------------------------------------
__global__ __launch_bounds__(256) void prep_wt(const float* __restrict__ W,
                                               _Float16* __restrict__ Wt) {
    __shared__ float t[32][33];
    const int k0 = blockIdx.x * 32;   // 1088 = 34*32
    const int n0 = blockIdx.y * 32;   // 1152 = 36*32
    const int tx = threadIdx.x, ty = threadIdx.y;
    for (int i = ty; i < 32; i += 8)
        t[i][tx] = W[(size_t)(k0 + i) * 1152 + n0 + tx];
    __syncthreads();
    for (int i = ty; i < 32; i += 8)
        Wt[(size_t)(n0 + i) * 1088 + k0 + tx] = (_Float16)t[tx][i];
}

// ---------------------------------------------------------------------------
// Fused encoder: enc1 -> enc2 -> enc3, 1 wave per graph (17 nodes), 4/block.
// Register-blocked: per thread the feature f is fixed; weights read once per
// k-step and reused across all nodes (independent accumulator chains).
// Writes A (16384 x 1088 f16).
// ---------------------------------------------------------------------------
#define EGPB 4
__global__ __launch_bounds__(256) void enc_kernel(
    const float* __restrict__ lx,  const float* __restrict__ rx,
    const float* __restrict__ lea, const float* __restrict__ rea,
    const float* __restrict__ w1l, const float* __restrict__ b1l,
    const float* __restrict__ w1u, const float* __restrict__ b1u,
    const float* __restrict__ w2l, const float* __restrict__ b2l,
    const float* __restrict__ w2u, const float* __restrict__ b2u,
    const float* __restrict__ w3l, const float* __restrict__ b3l,
    const float* __restrict__ w3u, const float* __restrict__ b3u,
    _Float16* __restrict__ Ae)
{
    __shared__ float s_w1l[144],  s_b1l[16], s_w1u[48],   s_b1u[16];
    __shared__ float s_w2l[1120], s_b2l[32], s_w2u[512],  s_b2u[32];
    __shared__ float s_w3l[4288], s_b3l[64], s_w3u[2048], s_b3u[64];
    __shared__ float sx[EGPB][17][3], sea_[EGPB][16][3];
    __shared__ float sh1[EGPB][17][16], sh2[EGPB][17][32];

    const int tid = threadIdx.x;
    for (int i = tid; i < 144;  i += 256) s_w1l[i] = w1l[i];
    for (int i = tid; i < 48;   i += 256) s_w1u[i] = w1u[i];
    for (int i = tid; i < 16;   i += 256) { s_b1l[i] = b1l[i]; s_b1u[i] = b1u[i]; }
    for (int i = tid; i < 1120; i += 256) s_w2l[i] = w2l[i];
    for (int i = tid; i < 512;  i += 256) s_w2u[i] = w2u[i];
    for (int i = tid; i < 32;   i += 256) { s_b2l[i] = b2l[i]; s_b2u[i] = b2u[i]; }
    for (int i = tid; i < 4288; i += 256) s_w3l[i] = w3l[i];
    for (int i = tid; i < 2048; i += 256) s_w3u[i] = w3u[i];
    for (int i = tid; i < 64;   i += 256) { s_b3l[i] = b3l[i]; s_b3u[i] = b3u[i]; }

    const int grp = tid >> 6, lane = tid & 63;
    const int g2 = blockIdx.x * EGPB + grp;      // 0..16383
    const float* xsrc  = (g2 < 8192) ? (lx  + (size_t)g2 * 51) : (rx  + (size_t)(g2 - 8192) * 51);
    const float* easrc = (g2 < 8192) ? (lea + (size_t)g2 * 48) : (rea + (size_t)(g2 - 8192) * 48);
    if (lane < 51) ((float*)sx[grp])[lane]   = xsrc[lane];
    if (lane < 48) ((float*)sea_[grp])[lane] = easrc[lane];
    __syncthreads();

    // ---- enc1: 17x16, f fixed per thread, nodes nl0+4j (guard nl<17) ----
    {
        const int f = lane & 15, nl0 = lane >> 4;
        float accu[5], msg[5];
        #pragma unroll
        for (int j = 0; j < 5; j++) { accu[j] = s_b1u[f]; msg[j] = s_b1l[f]; }
        #pragma unroll
        for (int c = 0; c < 3; c++) {
            const float wu = s_w1u[c * 16 + f];
            const float wl = s_w1l[c * 16 + f];
            const float wp = s_w1l[(3 + c) * 16 + f];
            const float we = s_w1l[(6 + c) * 16 + f];
            #pragma unroll
            for (int j = 0; j < 5; j++) {
                const int nl = nl0 + 4 * j;
                const int nv = nl < 17 ? nl : 0, np = nv ? nv - 1 : 0;
                const float xn = sx[grp][nv][c], xp = sx[grp][np][c];
                accu[j] += xn * wu;
                msg[j]  += xn * wl + xp * wp + sea_[grp][np][c] * we;
            }
        }
        #pragma unroll
        for (int j = 0; j < 5; j++) {
            const int nl = nl0 + 4 * j;
            if (nl < 17) sh1[grp][nl][f] = accu[j] + (nl ? lrelu(msg[j]) : 0.f);
        }
    }
    __syncthreads();

    // ---- enc2: 17x32, nodes nl0+2j (guard nl<17) ----
    {
        const int f = lane & 31, nl0 = lane >> 5;
        float accu[9], msg[9];
        #pragma unroll
        for (int j = 0; j < 9; j++) { accu[j] = s_b2u[f]; msg[j] = s_b2l[f]; }
        for (int c = 0; c < 16; c++) {
            const float wu = s_w2u[c * 32 + f];
            const float wl = s_w2l[c * 32 + f];
            const float wp = s_w2l[(16 + c) * 32 + f];
            #pragma unroll
            for (int j = 0; j < 9; j++) {
                const int nl = nl0 + 2 * j;
                const int nv = nl < 17 ? nl : 0, np = nv ? nv - 1 : 0;
                const float xn = sh1[grp][nv][c], xp = sh1[grp][np][c];
                accu[j] += xn * wu;
                msg[j]  += xn * wl + xp * wp;
            }
        }
        #pragma unroll
        for (int c = 0; c < 3; c++) {
            const float we = s_w2l[(32 + c) * 32 + f];
            #pragma unroll
            for (int j = 0; j < 9; j++) {
                const int nl = nl0 + 2 * j;
                const int nv = nl < 17 ? nl : 0, np = nv ? nv - 1 : 0;
                msg[j] += sea_[grp][np][c] * we;
            }
        }
        #pragma unroll
        for (int j = 0; j < 9; j++) {
            const int nl = nl0 + 2 * j;
            if (nl < 17) sh2[grp][nl][f] = accu[j] + (nl ? lrelu(msg[j]) : 0.f);
        }
    }
    __syncthreads();

    // ---- enc3: 17x64, f = lane, all 17 nodes chained per thread ----
    {
        const int f = lane;
        float accu[17], msg[17];
        #pragma unroll
        for (int j = 0; j < 17; j++) { accu[j] = s_b3u[f]; msg[j] = s_b3l[f]; }
        for (int c = 0; c < 32; c++) {
            const float wu = s_w3u[c * 64 + f];
            const float wl = s_w3l[c * 64 + f];
            const float wp = s_w3l[(32 + c) * 64 + f];
            float xprev = sh2[grp][0][c];
            accu[0] += xprev * wu;
            #pragma unroll
            for (int nl = 1; nl < 17; nl++) {
                const float xn = sh2[grp][nl][c];
                accu[nl] += xn * wu;
                msg[nl]  += xn * wl + xprev * wp;
                xprev = xn;
            }
        }
        #pragma unroll
        for (int c = 0; c < 3; c++) {
            const float we = s_w3l[(64 + c) * 64 + f];
            #pragma unroll
            for (int nl = 1; nl < 17; nl++)
                msg[nl] += sea_[grp][nl - 1][c] * we;
        }
        _Float16* arow = Ae + (size_t)g2 * 1088;
        #pragma unroll
        for (int nl = 0; nl < 17; nl++) {
            const float r = accu[nl] + (nl ? lrelu(msg[nl]) : 0.f);
            arow[nl * 64 + f] = (_Float16)r;
        }
    }
}

// ---------------------------------------------------------------------------
// trans GEMM fp16: Z = tanh(A(16384x1088) @ Wt^T(1152x1088) + b).
// 128x128 tile, BK=32, 4 waves x (64x64), mfma_f32_16x16x32_f16.
// global_load_lds 16B staging; LDS rows 64B with XOR swizzle
// slot = quad ^ ((row>>1)&3) -> 2-way bank alias on ds_read_b128 (free).
// ---------------------------------------------------------------------------
__global__ __launch_bounds__(256) void trans_gemm(
    const _Float16* __restrict__ A, const _Float16* __restrict__ Bt,
    const float* __restrict__ bias, float* __restrict__ Z)
{
    __shared__ __align__(16) _Float16 As[128 * 32];
    __shared__ __align__(16) _Float16 Bs[128 * 32];
    const int tid = threadIdx.x;
    const int bm = blockIdx.x * 128, bn = blockIdx.y * 128;
    const int lane = tid & 63, wave = tid >> 6;
    const int wr = wave >> 1, wc = wave & 1;
    const int quad = lane >> 4, l16 = lane & 15;

    // --- staging precompute: wave handles rows [wave*32, wave*32+32) of both
    const int row0 = wave * 32 + (lane >> 2);
    const int row1 = row0 + 16;
    const int q0 = (lane & 3) ^ ((row0 >> 1) & 3);
    const int q1 = (lane & 3) ^ ((row1 >> 1) & 3);
    const size_t gA0 = (size_t)(bm + row0) * 1088 + q0 * 8;
    const size_t gA1 = (size_t)(bm + row1) * 1088 + q1 * 8;
    const size_t gB0 = (size_t)(bn + row0) * 1088 + q0 * 8;
    const size_t gB1 = (size_t)(bn + row1) * 1088 + q1 * 8;
    _Float16* ldsb0A = &As[(wave * 32) * 32];        // wave-uniform bases
    _Float16* ldsb1A = &As[(wave * 32 + 16) * 32];
    _Float16* ldsb0B = &Bs[(wave * 32) * 32];
    _Float16* ldsb1B = &Bs[(wave * 32 + 16) * 32];

    // --- fragment read offsets (halves), k0-independent
    int offA[4], offB[4];
    #pragma unroll
    for (int i = 0; i < 4; i++) {
        const int ma = wr * 64 + i * 16 + l16;
        offA[i] = ma * 32 + (quad ^ ((ma >> 1) & 3)) * 8;
        const int nb = wc * 64 + i * 16 + l16;
        offB[i] = nb * 32 + (quad ^ ((nb >> 1) & 3)) * 8;
    }

    f32x4 acc[4][4];
    #pragma unroll
    for (int i = 0; i < 4; i++)
        #pragma unroll
        for (int j = 0; j < 4; j++)
            #pragma unroll
            for (int r = 0; r < 4; r++) acc[i][j][r] = 0.f;

    for (int k0 = 0; k0 < 1088; k0 += 32) {
        __syncthreads();                       // prev reads done before overwrite
        gload_lds16(A + gA0 + k0, ldsb0A);
        gload_lds16(A + gA1 + k0, ldsb1A);
        gload_lds16(Bt + gB0 + k0, ldsb0B);
        gload_lds16(Bt + gB1 + k0, ldsb1B);
        __syncthreads();                       // drains vmcnt, data visible
        f16x8 af[4], bfr[4];
        #pragma unroll
        for (int mi = 0; mi < 4; mi++) af[mi]  = *(const f16x8*)&As[offA[mi]];
        #pragma unroll
        for (int ni = 0; ni < 4; ni++) bfr[ni] = *(const f16x8*)&Bs[offB[ni]];
        #pragma unroll
        for (int mi = 0; mi < 4; mi++)
            #pragma unroll
            for (int ni = 0; ni < 4; ni++)
                acc[mi][ni] = __builtin_amdgcn_mfma_f32_16x16x32_f16(
                    af[mi], bfr[ni], acc[mi][ni], 0, 0, 0);
    }

    // epilogue: bias + tanh; D layout col=lane&15, row=quad*4+r
    #pragma unroll
    for (int mi = 0; mi < 4; mi++) {
        #pragma unroll
        for (int ni = 0; ni < 4; ni++) {
            const int n = bn + wc * 64 + ni * 16 + l16;
            const float bv = bias[n];
            #pragma unroll
            for (int r = 0; r < 4; r++) {
                const int m = bm + wr * 64 + mi * 16 + quad * 4 + r;
                Z[(size_t)m * 1152 + n] = tanh_fast(acc[mi][ni][r] + bv);
            }
        }
    }
}

// ---------------------------------------------------------------------------
// Fused decoder + FK: dec1 -> dec2 -> dec3 -> angles -> FK.
// 1 wave per graph (18 nodes), 4 graphs/block, register-blocked like encoder.
// ---------------------------------------------------------------------------
#define DGPB 4
__global__ __launch_bounds__(256) void dec_kernel(
    const float* __restrict__ Zc,  const float* __restrict__ tea,
    const float* __restrict__ lo_, const float* __restrict__ up_,
    const float* __restrict__ off_, const int* __restrict__ par_,
    const float* __restrict__ ax_,
    const float* __restrict__ w1l, const float* __restrict__ b1l,
    const float* __restrict__ w1u, const float* __restrict__ b1u,
    const float* __restrict__ w2l, const float* __restrict__ b2l,
    const float* __restrict__ w2u, const float* __restrict__ b2u,
    const float* __restrict__ w3l, const float* __restrict__ b3l,
    const float* __restrict__ w3u, const float* __restrict__ b3u,
    float* __restrict__ out)
{
    __shared__ float s_w1l[4416], s_w1u[2112], s_b1l[32], s_b1u[32];
    __shared__ float s_w2l[1120], s_w2u[512],  s_b2l[16], s_b2u[16];
    __shared__ float s_w3l[38],   s_w3u[16];
    __shared__ float s_b3l1, s_b3u1;
    __shared__ float sxd[DGPB][18][66];
    __shared__ float sea_[DGPB][17][6];
    __shared__ float sh1[DGPB][18][32];
    __shared__ float sh2[DGPB][18][16];
    __shared__ float sang[DGPB][18];

    const int tid = threadIdx.x;
    for (int i = tid; i < 4416; i += 256) s_w1l[i] = w1l[i];
    for (int i = tid; i < 2112; i += 256) s_w1u[i] = w1u[i];
    for (int i = tid; i < 32;   i += 256) { s_b1l[i] = b1l[i]; s_b1u[i] = b1u[i]; }
    for (int i = tid; i < 1120; i += 256) s_w2l[i] = w2l[i];
    for (int i = tid; i < 512;  i += 256) s_w2u[i] = w2u[i];
    for (int i = tid; i < 16;   i += 256) { s_b2l[i] = b2l[i]; s_b2u[i] = b2u[i]; s_w3u[i] = w3u[i]; }
    for (int i = tid; i < 38;   i += 256) s_w3l[i] = w3l[i];
    if (tid == 0) { s_b3l1 = b3l[0]; s_b3u1 = b3u[0]; }

    const int grp = tid >> 6, lane = tid & 63;
    const int g2 = blockIdx.x * DGPB + grp;     // 0..16383
    const int gb = (g2 & 8191) * 18;            // per-hand array base

    for (int i = lane; i < 1152; i += 64)
        sxd[grp][i >> 6][i & 63] = Zc[(size_t)g2 * 1152 + i];
    if (lane < 18) {
        sxd[grp][lane][64] = lo_[gb + lane];
        sxd[grp][lane][65] = up_[gb + lane];
    }
    if (lane < 51) {
        ((float*)sea_[grp])[lane]      = tea[(size_t)(g2 & 8191) * 102 + lane];
        ((float*)sea_[grp])[lane + 51] = tea[(size_t)(g2 & 8191) * 102 + 51 + lane];
    }
    __syncthreads();

    // ---- dec1: 18x32, nodes nl0+2j, j=0..8 (all valid) ----
    {
        const int f = lane & 31, nl0 = lane >> 5;
        float accu[9], msg[9];
        #pragma unroll
        for (int j = 0; j < 9; j++) { accu[j] = s_b1u[f]; msg[j] = s_b1l[f]; }
        for (int c = 0; c < 66; c++) {
            const float wu = s_w1u[c * 32 + f];
            const float wl = s_w1l[c * 32 + f];
            const float wp = s_w1l[(66 + c) * 32 + f];
            #pragma unroll
            for (int j = 0; j < 9; j++) {
                const int nl = nl0 + 2 * j, np = nl ? nl - 1 : 0;
                const float xn = sxd[grp][nl][c], xp = sxd[grp][np][c];
                accu[j] += xn * wu;
                msg[j]  += xn * wl + xp * wp;
            }
        }
        #pragma unroll
        for (int c = 0; c < 6; c++) {
            const float we = s_w1l[(132 + c) * 32 + f];
            #pragma unroll
            for (int j = 0; j < 9; j++) {
                const int nl = nl0 + 2 * j, np = nl ? nl - 1 : 0;
                msg[j] += sea_[grp][np][c] * we;
            }
        }
        #pragma unroll
        for (int j = 0; j < 9; j++) {
            const int nl = nl0 + 2 * j;
            sh1[grp][nl][f] = accu[j] + (nl ? lrelu(msg[j]) : 0.f);
        }
    }
    __syncthreads();

    // ---- dec2: 18x16, nodes nl0+4j, j=0..4 (guard nl<18) ----
    {
        const int f = lane & 15, nl0 = lane >> 4;
        float accu[5], msg[5];
        #pragma unroll
        for (int j = 0; j < 5; j++) { accu[j] = s_b2u[f]; msg[j] = s_b2l[f]; }
        for (int c = 0; c < 32; c++) {
            const float wu = s_w2u[c * 16 + f];
            const float wl = s_w2l[c * 16 + f];
            const float wp = s_w2l[(32 + c) * 16 + f];
            #pragma unroll
            for (int j = 0; j < 5; j++) {
                const int nl = nl0 + 4 * j;
                const int nv = nl < 18 ? nl : 0, np = nv ? nv - 1 : 0;
                const float xn = sh1[grp][nv][c], xp = sh1[grp][np][c];
                accu[j] += xn * wu;
                msg[j]  += xn * wl + xp * wp;
            }
        }
        #pragma unroll
        for (int c = 0; c < 6; c++) {
            const float we = s_w2l[(64 + c) * 16 + f];
            #pragma unroll
            for (int j = 0; j < 5; j++) {
                const int nl = nl0 + 4 * j;
                const int nv = nl < 18 ? nl : 0, np = nv ? nv - 1 : 0;
                msg[j] += sea_[grp][np][c] * we;
            }
        }
        #pragma unroll
        for (int j = 0; j < 5; j++) {
            const int nl = nl0 + 4 * j;
            if (nl < 18) sh2[grp][nl][f] = accu[j] + (nl ? lrelu(msg[j]) : 0.f);
        }
    }
    __syncthreads();

    // ---- dec3 (18x1) + tanh + angle ----
    if (lane < 18) {
        const int nl = lane;
        const float* hn = sh2[grp][nl];
        float acc = s_b3u1;
        #pragma unroll
        for (int c = 0; c < 16; c++) acc += hn[c] * s_w3u[c];
        if (nl > 0) {
            const float* hp = sh2[grp][nl - 1];
            const float* e  = sea_[grp][nl - 1];
            float m = s_b3l1;
            #pragma unroll
            for (int c = 0; c < 16; c++) m += hn[c] * s_w3l[c];
            #pragma unroll
            for (int c = 0; c < 16; c++) m += hp[c] * s_w3l[16 + c];
            #pragma unroll
            for (int c = 0; c < 6;  c++) m += e[c]  * s_w3l[32 + c];
            acc += lrelu(m);
        }
        const float hd = tanh_fast(acc);
        const float lo = sxd[grp][nl][64], up = sxd[grp][nl][65];
        const float ang = lo + (up - lo) * (hd + 1.f) * 0.5f;
        sang[grp][nl] = ang;
        const size_t abase = (g2 < 8192) ? (size_t)ZSIZE + (size_t)g2 * 18
                                         : (size_t)ZSIZE + AHALF + PHALF + (size_t)(g2 - 8192) * 18;
        out[abase + nl] = ang;
    }
    __syncthreads();

    // ---- FK: sequential 18-joint chain, one thread per graph ----
    if (lane == 0) {
        const size_t pbase = (g2 < 8192)
            ? (size_t)ZSIZE + AHALF + (size_t)g2 * 54
            : (size_t)ZSIZE + AHALF + PHALF + AHALF + (size_t)(g2 - 8192) * 54;
        float R[9], p[3];
        for (int j = 0; j < 18; j++) {
            const int m = gb + j;
            const float a0 = ax_[m * 3], a1 = ax_[m * 3 + 1], a2 = ax_[m * 3 + 2];
            const float o0 = off_[m * 3], o1 = off_[m * 3 + 1], o2 = off_[m * 3 + 2];
            const float ang = sang[grp][j];
            float s, c;
            __sincosf(ang, &s, &c);
            const float omc = 1.f - c;
            const float n2 = a0 * a0 + a1 * a1 + a2 * a2;
            float Rl[9];
            Rl[0] = 1.f + omc * (a0 * a0 - n2);
            Rl[1] = -s * a2 + omc * a0 * a1;
            Rl[2] =  s * a1 + omc * a0 * a2;
            Rl[3] =  s * a2 + omc * a1 * a0;
            Rl[4] = 1.f + omc * (a1 * a1 - n2);
            Rl[5] = -s * a0 + omc * a1 * a2;
            Rl[6] = -s * a1 + omc * a2 * a0;
            Rl[7] =  s * a0 + omc * a2 * a1;
            Rl[8] = 1.f + omc * (a2 * a2 - n2);
            if (par_[m] < 0) {
                #pragma unroll
                for (int q = 0; q < 9; q++) R[q] = Rl[q];
                p[0] = o0; p[1] = o1; p[2] = o2;
            } else {
                float Rn[9];
                #pragma unroll
                for (int r = 0; r < 3; r++) {
                    Rn[r * 3 + 0] = R[r * 3] * Rl[0] + R[r * 3 + 1] * Rl[3] + R[r * 3 + 2] * Rl[6];
                    Rn[r * 3 + 1] = R[r * 3] * Rl[1] + R[r * 3 + 1] * Rl[4] + R[r * 3 + 2] * Rl[7];
                    Rn[r * 3 + 2] = R[r * 3] * Rl[2] + R[r * 3 + 1] * Rl[5] + R[r * 3 + 2] * Rl[8];
                }
                const float q0 = p[0] + R[0] * o0 + R[1] * o1 + R[2] * o2;
                const float q1 = p[1] + R[3] * o0 + R[4] * o1 + R[5] * o2;
                const float q2 = p[2] + R[6] * o0 + R[7] * o1 + R[8] * o2;
                #pragma unroll
                for (int q = 0; q < 9; q++) R[q] = Rn[q];
                p[0] = q0; p[1] = q1; p[2] = q2;
            }
            out[pbase + j * 3 + 0] = p[0];
            out[pbase + j * 3 + 1] = p[1];
            out[pbase + j * 3 + 2] = p[2];
        }
    }
}

// ---------------------------------------------------------------------------
extern "C" void kernel_launch(void* const* d_in, const int* in_sizes, int n_in,
                              void* d_out, int out_size, void* d_ws, size_t ws_size,
                              hipStream_t stream)
{
    int i_tw, i_tb, i_d1, i_d2, i_d3;
    if (n_in > 27 && in_sizes[26] == 1088 * 1152) {
        i_tw = 26; i_tb = 27; i_d1 = 28; i_d2 = 32; i_d3 = 36;
    } else {
        i_d1 = 26; i_d2 = 30; i_d3 = 34; i_tw = 38; i_tb = 39;
    }
    auto fp = [&](int i) { return (const float*)d_in[i]; };

    _Float16* Ae = (_Float16*)d_ws;                          // 16384x1088 f16
    _Float16* Wt = (_Float16*)((char*)d_ws + 35651584);      // 1152x1088 f16

    prep_wt<<<dim3(34, 36), dim3(32, 8), 0, stream>>>(fp(i_tw), Wt);

    enc_kernel<<<4096, 256, 0, stream>>>(
        fp(0), fp(1), fp(4), fp(5),
        fp(14), fp(15), fp(16), fp(17),
        fp(18), fp(19), fp(20), fp(21),
        fp(22), fp(23), fp(24), fp(25), Ae);

    trans_gemm<<<dim3(128, 9), 256, 0, stream>>>(Ae, Wt, fp(i_tb), (float*)d_out);

    dec_kernel<<<4096, 256, 0, stream>>>(
        (const float*)d_out, fp(7), fp(8), fp(9), fp(10),
        (const int*)d_in[11], fp(12),
        fp(i_d1), fp(i_d1 + 1), fp(i_d1 + 2), fp(i_d1 + 3),
        fp(i_d2), fp(i_d2 + 1), fp(i_d2 + 2), fp(i_d2 + 3),
        fp(i_d3), fp(i_d3 + 1), fp(i_d3 + 2), fp(i_d3 + 3),
        (float*)d_out);
}

// Round 5
// 386.935 us; speedup vs baseline: 2.5046x; 1.4770x over previous
//
#include <hip/hip_runtime.h>
#include <hip/hip_bf16.h>
#include <stdint.h>

// ---------------------------------------------------------------------------
// HandNet R5: R4 with the enc3 weight-stage size bug fixed (832 -> 1664 uint4;
// 128x104 fp16 = 1664 uint4, the old count loaded only the msg cols and left
// stale enc2 weights under the u cols).
// All GNN layers on MFMA via combined [Wl|Wu] packed weights.
// Chain topology: node k's incoming message comes from node k-1 (src=dst-1),
// so the A-operand [x_dst | x_src | ea] is read region-wise from LDS without
// materializing (region widths padded to multiples of 8 fp16 = one chunk).
// ---------------------------------------------------------------------------

#define ZSIZE 18874368   // 16384*1152  (z output)
#define AHALF 147456     // 8192*18     (ang half)
#define PHALF 442368     // AHALF*3     (pos half)

// ws layout (bytes)
#define WS_AE 0                  // 16384x1088 fp16 = 35651584
#define WS_WT 35651584           // 1152x1088 fp16  = 2506752
#define WS_PACK 38158336         // packed layer weights, 33280 fp16

// pack offsets (fp16 units) and padded row strides
#define P_E1 0        // enc1: 32 x 40
#define P_E2 1280     // enc2: 64 x 72
#define P_E3 5888     // enc3: 128 x 104
#define P_D1 19200    // dec1: 64 x 168
#define P_D2 29952    // dec2: 32 x 104

using f32x4 = __attribute__((ext_vector_type(4))) float;
using f16x8 = __attribute__((ext_vector_type(8))) _Float16;

__device__ __forceinline__ float tanh_fast(float x) {
    x = fminf(40.f, fmaxf(-40.f, x));
    float e = __expf(2.f * x);
    return (e - 1.f) / (e + 1.f);
}
__device__ __forceinline__ float lrelu(float x) { return x > 0.f ? x : 0.01f * x; }

__device__ __forceinline__ void gload_lds16(const void* g, void* l) {
    __builtin_amdgcn_global_load_lds(
        (__attribute__((address_space(1))) unsigned int*)g,
        (__attribute__((address_space(3))) unsigned int*)l, 16, 0, 0);
}

// ---------------------------------------------------------------------------
// pack_weights: build combined [msg | u] weight matrices, fp16, B-fragment
// layout [n][KpP] (row stride padded for LDS bank spread).
// k-regions: [0,din) -> Wl dst rows; [K0,K0+din) -> Wl src rows;
//            [2K0, 2K0+ed) -> Wl edge rows; u-cols (n>=N): [0,din) -> Wu.
// ---------------------------------------------------------------------------
__global__ __launch_bounds__(256) void pack_weights(
    _Float16* __restrict__ P,
    const float* __restrict__ e1l, const float* __restrict__ e1u,
    const float* __restrict__ e2l, const float* __restrict__ e2u,
    const float* __restrict__ e3l, const float* __restrict__ e3u,
    const float* __restrict__ d1l, const float* __restrict__ d1u,
    const float* __restrict__ d2l, const float* __restrict__ d2u)
{
    const int p = blockIdx.x;
    const int e = blockIdx.y * 256 + threadIdx.x;
    int Np, Kp, KpP, N, din, ed, K0, off; const float *Wl, *Wu;
    switch (p) {
      case 0:  Np=32;  Kp=32;  KpP=40;  N=16; din=3;  ed=3; K0=8;  off=P_E1; Wl=e1l; Wu=e1u; break;
      case 1:  Np=64;  Kp=64;  KpP=72;  N=32; din=16; ed=3; K0=24; off=P_E2; Wl=e2l; Wu=e2u; break;
      case 2:  Np=128; Kp=96;  KpP=104; N=64; din=32; ed=3; K0=40; off=P_E3; Wl=e3l; Wu=e3u; break;
      case 3:  Np=64;  Kp=160; KpP=168; N=32; din=66; ed=6; K0=72; off=P_D1; Wl=d1l; Wu=d1u; break;
      default: Np=32;  Kp=96;  KpP=104; N=16; din=32; ed=6; K0=40; off=P_D2; Wl=d2l; Wu=d2u; break;
    }
    if (e >= Np * KpP) return;
    const int n = e / KpP, k = e - n * KpP;
    float v = 0.f;
    if (k < Kp) {
        if (n < N) {
            if (k < din)                          v = Wl[k * N + n];
            else if (k >= K0 && k < K0 + din)     v = Wl[(din + k - K0) * N + n];
            else if (k >= 2*K0 && k < 2*K0 + ed)  v = Wl[(2*din + k - 2*K0) * N + n];
        } else {
            if (k < din) v = Wu[k * N + (n - N)];
        }
    }
    P[off + e] = (_Float16)v;
}

// ---------------------------------------------------------------------------
// Wt prep: trans_w (1088 x 1152 f32) -> Wt (1152 x 1088 f16) transpose.
// ---------------------------------------------------------------------------
__global__ __launch_bounds__(256) void prep_wt(const float* __restrict__ W,
                                               _Float16* __restrict__ Wt) {
    __shared__ float t[32][33];
    const int k0 = blockIdx.x * 32;
    const int n0 = blockIdx.y * 32;
    const int tx = threadIdx.x, ty = threadIdx.y;
    for (int i = ty; i < 32; i += 8)
        t[i][tx] = W[(size_t)(k0 + i) * 1152 + n0 + tx];
    __syncthreads();
    for (int i = ty; i < 32; i += 8)
        Wt[(size_t)(n0 + i) * 1088 + k0 + tx] = (_Float16)t[tx][i];
}

// ---------------------------------------------------------------------------
// Fused encoder on MFMA: 4 graphs/block, nodes padded to 20 -> M=80 (5 Mt).
// Activation strides (fp16): x 8, ea 16, h1 24, h2 40 (all zero-padded).
// LDS map (fp16 units): SX 0(640) | EA 640(1280) | H1 1920(1920) |
//                       H2 3840(3200) | WQ 7040(13312) -> pool 20352.
// ---------------------------------------------------------------------------
#define E_SX 0
#define E_EA 640
#define E_H1 1920
#define E_H2 3840
#define E_WQ 7040

__global__ __launch_bounds__(256) void enc_kernel(
    const float* __restrict__ lx,  const float* __restrict__ rx,
    const float* __restrict__ lea, const float* __restrict__ rea,
    const float* __restrict__ b1l, const float* __restrict__ b1u,
    const float* __restrict__ b2l, const float* __restrict__ b2u,
    const float* __restrict__ b3l, const float* __restrict__ b3u,
    const _Float16* __restrict__ pack,
    _Float16* __restrict__ Ae)
{
    __shared__ __align__(16) _Float16 sm[20352];
    __shared__ float sb[224];

    const int tid = threadIdx.x;
    const int wave = tid >> 6, lane = tid & 63;
    const int quad = lane >> 4, l16 = lane & 15;
    const int g2b = blockIdx.x * 4;

    // zero activation pool (7040 fp16 = 3520 u32)
    for (int i = tid; i < 3520; i += 256) ((uint32_t*)sm)[i] = 0u;
    // enc1 weights (1280 fp16 = 160 uint4)
    { uint4* d = (uint4*)&sm[E_WQ]; const uint4* s = (const uint4*)(pack + P_E1);
      for (int i = tid; i < 160; i += 256) d[i] = s[i]; }
    for (int i = tid; i < 16; i += 256) { sb[i] = b1l[i]; sb[16 + i] = b1u[i]; }
    for (int i = tid; i < 32; i += 256) { sb[32 + i] = b2l[i]; sb[64 + i] = b2u[i]; }
    for (int i = tid; i < 64; i += 256) { sb[96 + i] = b3l[i]; sb[160 + i] = b3u[i]; }
    __syncthreads();

    // stage x, ea (4 graphs, all on same hand since g2b % 4 == 0)
    const float* xs = (g2b < 8192) ? lx  + (size_t)g2b * 51 : rx  + (size_t)(g2b - 8192) * 51;
    const float* es = (g2b < 8192) ? lea + (size_t)g2b * 48 : rea + (size_t)(g2b - 8192) * 48;
    for (int i = tid; i < 204; i += 256) {
        int g = i / 51, j = i - g * 51, node = j / 3, c = j - node * 3;
        sm[E_SX + (g * 20 + node) * 8 + c] = (_Float16)xs[i];
    }
    for (int i = tid; i < 192; i += 256) {
        int g = i / 48, j = i - g * 48, node = j / 3, c = j - node * 3;
        sm[E_EA + (g * 20 + node) * 16 + c] = (_Float16)es[i];
    }
    __syncthreads();

    // M-tiles owned: wave, and wave+4 for wave 0
    int mts[2] = { wave, wave + 4 };
    const bool has[2] = { true, wave == 0 };
    int gN[2], ndN[2], npN[2];
    #pragma unroll
    for (int t = 0; t < 2; t++) {
        const int r16 = mts[t] * 16 + l16;
        gN[t] = r16 / 20; ndN[t] = r16 - gN[t] * 20;
        npN[t] = ndN[t] ? ndN[t] - 1 : 0;
    }

    // ---- enc1: K'=32 (1 Kt), N'=32 (2 Nt) ----
    {
        f32x4 acc[2][2];
        #pragma unroll
        for (int t = 0; t < 2; t++)
            #pragma unroll
            for (int n = 0; n < 2; n++)
                #pragma unroll
                for (int r = 0; r < 4; r++) acc[t][n][r] = 0.f;
        f16x8 bfr[2];
        #pragma unroll
        for (int nt = 0; nt < 2; nt++)
            bfr[nt] = *(const f16x8*)&sm[E_WQ + (nt * 16 + l16) * 40 + quad * 8];
        #pragma unroll
        for (int t = 0; t < 2; t++) if (has[t]) {
            const int aD = E_SX + (gN[t] * 20 + ndN[t]) * 8;
            const int aS = E_SX + (gN[t] * 20 + npN[t]) * 8;
            const int aE = E_EA + (gN[t] * 20 + npN[t]) * 16;
            const int ch = quad;
            const int off = ch < 1 ? aD : (ch < 2 ? aS : aE + (ch - 2) * 8);
            f16x8 af = *(const f16x8*)&sm[off];
            #pragma unroll
            for (int nt = 0; nt < 2; nt++)
                acc[t][nt] = __builtin_amdgcn_mfma_f32_16x16x32_f16(af, bfr[nt], acc[t][nt], 0, 0, 0);
        }
        const int f = l16;
        #pragma unroll
        for (int t = 0; t < 2; t++) if (has[t]) {
            #pragma unroll
            for (int r = 0; r < 4; r++) {
                const int row = mts[t] * 16 + quad * 4 + r;
                const int g = row / 20, nd = row - g * 20;
                if (nd < 17) {
                    const float msg = acc[t][0][r] + sb[f];
                    const float u   = acc[t][1][r] + sb[16 + f];
                    sm[E_H1 + (g * 20 + nd) * 24 + f] =
                        (_Float16)(u + (nd ? lrelu(msg) : 0.f));
                }
            }
        }
    }
    __syncthreads();
    { uint4* d = (uint4*)&sm[E_WQ]; const uint4* s = (const uint4*)(pack + P_E2);
      for (int i = tid; i < 576; i += 256) d[i] = s[i]; }   // 4608 fp16 = 576 uint4
    __syncthreads();

    // ---- enc2: K'=64 (2 Kt), N'=64 (4 Nt) ----
    {
        f32x4 acc[2][4];
        #pragma unroll
        for (int t = 0; t < 2; t++)
            #pragma unroll
            for (int n = 0; n < 4; n++)
                #pragma unroll
                for (int r = 0; r < 4; r++) acc[t][n][r] = 0.f;
        #pragma unroll
        for (int Kt = 0; Kt < 2; Kt++) {
            f16x8 bfr[4];
            #pragma unroll
            for (int nt = 0; nt < 4; nt++)
                bfr[nt] = *(const f16x8*)&sm[E_WQ + (nt * 16 + l16) * 72 + Kt * 32 + quad * 8];
            #pragma unroll
            for (int t = 0; t < 2; t++) if (has[t]) {
                const int aD = E_H1 + (gN[t] * 20 + ndN[t]) * 24;
                const int aS = E_H1 + (gN[t] * 20 + npN[t]) * 24;
                const int aE = E_EA + (gN[t] * 20 + npN[t]) * 16;
                const int ch = Kt * 4 + quad;
                const int off = ch < 3 ? aD + ch * 8
                              : (ch < 6 ? aS + (ch - 3) * 8 : aE + (ch - 6) * 8);
                f16x8 af = *(const f16x8*)&sm[off];
                #pragma unroll
                for (int nt = 0; nt < 4; nt++)
                    acc[t][nt] = __builtin_amdgcn_mfma_f32_16x16x32_f16(af, bfr[nt], acc[t][nt], 0, 0, 0);
            }
        }
        #pragma unroll
        for (int ntm = 0; ntm < 2; ntm++) {
            const int f = ntm * 16 + l16;
            #pragma unroll
            for (int t = 0; t < 2; t++) if (has[t]) {
                #pragma unroll
                for (int r = 0; r < 4; r++) {
                    const int row = mts[t] * 16 + quad * 4 + r;
                    const int g = row / 20, nd = row - g * 20;
                    if (nd < 17) {
                        const float msg = acc[t][ntm][r]     + sb[32 + f];
                        const float u   = acc[t][ntm + 2][r] + sb[64 + f];
                        sm[E_H2 + (g * 20 + nd) * 40 + f] =
                            (_Float16)(u + (nd ? lrelu(msg) : 0.f));
                    }
                }
            }
        }
    }
    __syncthreads();
    { uint4* d = (uint4*)&sm[E_WQ]; const uint4* s = (const uint4*)(pack + P_E3);
      for (int i = tid; i < 1664; i += 256) d[i] = s[i]; }  // 13312 fp16 = 1664 uint4 (FIX)
    __syncthreads();

    // ---- enc3: K'=96 (3 Kt), N'=128 (8 Nt) -> global Ae ----
    {
        f32x4 acc[2][8];
        #pragma unroll
        for (int t = 0; t < 2; t++)
            #pragma unroll
            for (int n = 0; n < 8; n++)
                #pragma unroll
                for (int r = 0; r < 4; r++) acc[t][n][r] = 0.f;
        #pragma unroll
        for (int Kt = 0; Kt < 3; Kt++) {
            f16x8 bfr[8];
            #pragma unroll
            for (int nt = 0; nt < 8; nt++)
                bfr[nt] = *(const f16x8*)&sm[E_WQ + (nt * 16 + l16) * 104 + Kt * 32 + quad * 8];
            #pragma unroll
            for (int t = 0; t < 2; t++) if (has[t]) {
                const int aD = E_H2 + (gN[t] * 20 + ndN[t]) * 40;
                const int aS = E_H2 + (gN[t] * 20 + npN[t]) * 40;
                const int aE = E_EA + (gN[t] * 20 + npN[t]) * 16;
                const int ch = Kt * 4 + quad;
                const int off = ch < 5 ? aD + ch * 8
                              : (ch < 10 ? aS + (ch - 5) * 8 : aE + (ch - 10) * 8);
                f16x8 af = *(const f16x8*)&sm[off];
                #pragma unroll
                for (int nt = 0; nt < 8; nt++)
                    acc[t][nt] = __builtin_amdgcn_mfma_f32_16x16x32_f16(af, bfr[nt], acc[t][nt], 0, 0, 0);
            }
        }
        #pragma unroll
        for (int ntm = 0; ntm < 4; ntm++) {
            const int f = ntm * 16 + l16;
            #pragma unroll
            for (int t = 0; t < 2; t++) if (has[t]) {
                #pragma unroll
                for (int r = 0; r < 4; r++) {
                    const int row = mts[t] * 16 + quad * 4 + r;
                    const int g = row / 20, nd = row - g * 20;
                    if (nd < 17) {
                        const float msg = acc[t][ntm][r]     + sb[96 + f];
                        const float u   = acc[t][ntm + 4][r] + sb[160 + f];
                        Ae[(size_t)(g2b + g) * 1088 + nd * 64 + f] =
                            (_Float16)(u + (nd ? lrelu(msg) : 0.f));
                    }
                }
            }
        }
    }
}

// ---------------------------------------------------------------------------
// trans GEMM fp16 (unchanged, validated in R2).
// ---------------------------------------------------------------------------
__global__ __launch_bounds__(256) void trans_gemm(
    const _Float16* __restrict__ A, const _Float16* __restrict__ Bt,
    const float* __restrict__ bias, float* __restrict__ Z)
{
    __shared__ __align__(16) _Float16 As[128 * 32];
    __shared__ __align__(16) _Float16 Bs[128 * 32];
    const int tid = threadIdx.x;
    const int bm = blockIdx.x * 128, bn = blockIdx.y * 128;
    const int lane = tid & 63, wave = tid >> 6;
    const int wr = wave >> 1, wc = wave & 1;
    const int quad = lane >> 4, l16 = lane & 15;

    const int row0 = wave * 32 + (lane >> 2);
    const int row1 = row0 + 16;
    const int q0 = (lane & 3) ^ ((row0 >> 1) & 3);
    const int q1 = (lane & 3) ^ ((row1 >> 1) & 3);
    const size_t gA0 = (size_t)(bm + row0) * 1088 + q0 * 8;
    const size_t gA1 = (size_t)(bm + row1) * 1088 + q1 * 8;
    const size_t gB0 = (size_t)(bn + row0) * 1088 + q0 * 8;
    const size_t gB1 = (size_t)(bn + row1) * 1088 + q1 * 8;
    _Float16* ldsb0A = &As[(wave * 32) * 32];
    _Float16* ldsb1A = &As[(wave * 32 + 16) * 32];
    _Float16* ldsb0B = &Bs[(wave * 32) * 32];
    _Float16* ldsb1B = &Bs[(wave * 32 + 16) * 32];

    int offA[4], offB[4];
    #pragma unroll
    for (int i = 0; i < 4; i++) {
        const int ma = wr * 64 + i * 16 + l16;
        offA[i] = ma * 32 + (quad ^ ((ma >> 1) & 3)) * 8;
        const int nb = wc * 64 + i * 16 + l16;
        offB[i] = nb * 32 + (quad ^ ((nb >> 1) & 3)) * 8;
    }

    f32x4 acc[4][4];
    #pragma unroll
    for (int i = 0; i < 4; i++)
        #pragma unroll
        for (int j = 0; j < 4; j++)
            #pragma unroll
            for (int r = 0; r < 4; r++) acc[i][j][r] = 0.f;

    for (int k0 = 0; k0 < 1088; k0 += 32) {
        __syncthreads();
        gload_lds16(A + gA0 + k0, ldsb0A);
        gload_lds16(A + gA1 + k0, ldsb1A);
        gload_lds16(Bt + gB0 + k0, ldsb0B);
        gload_lds16(Bt + gB1 + k0, ldsb1B);
        __syncthreads();
        f16x8 af[4], bfr[4];
        #pragma unroll
        for (int mi = 0; mi < 4; mi++) af[mi]  = *(const f16x8*)&As[offA[mi]];
        #pragma unroll
        for (int ni = 0; ni < 4; ni++) bfr[ni] = *(const f16x8*)&Bs[offB[ni]];
        #pragma unroll
        for (int mi = 0; mi < 4; mi++)
            #pragma unroll
            for (int ni = 0; ni < 4; ni++)
                acc[mi][ni] = __builtin_amdgcn_mfma_f32_16x16x32_f16(
                    af[mi], bfr[ni], acc[mi][ni], 0, 0, 0);
    }

    #pragma unroll
    for (int mi = 0; mi < 4; mi++) {
        #pragma unroll
        for (int ni = 0; ni < 4; ni++) {
            const int n = bn + wc * 64 + ni * 16 + l16;
            const float bv = bias[n];
            #pragma unroll
            for (int r = 0; r < 4; r++) {
                const int m = bm + wr * 64 + mi * 16 + quad * 4 + r;
                Z[(size_t)m * 1152 + n] = tanh_fast(acc[mi][ni][r] + bv);
            }
        }
    }
}

// ---------------------------------------------------------------------------
// Fused decoder + FK on MFMA: 8 graphs/block, M=160 (10 Mt).
// Strides (fp16): xd 72, ea 16, h1 40, h2 16.
// LDS map (fp16): XD 0(11520) | EA 11520(2560) | H1 14080(6400) |
//                 H2 20480(2560) | WQ 23040(10752) -> pool 33792.
// ---------------------------------------------------------------------------
#define D_XD 0
#define D_EA 11520
#define D_H1 14080
#define D_H2 20480
#define D_WQ 23040
#define SB_B1L 0
#define SB_B1U 32
#define SB_B2L 64
#define SB_B2U 80
#define SB_W3L 96
#define SB_W3U 134
#define SB_B3L 150
#define SB_B3U 151
#define SB_ANG 152   // 144 floats

__global__ __launch_bounds__(256) void dec_kernel(
    const float* __restrict__ Zc,  const float* __restrict__ tea,
    const float* __restrict__ lo_, const float* __restrict__ up_,
    const float* __restrict__ off_, const int* __restrict__ par_,
    const float* __restrict__ ax_,
    const float* __restrict__ b1l, const float* __restrict__ b1u,
    const float* __restrict__ b2l, const float* __restrict__ b2u,
    const float* __restrict__ w3l, const float* __restrict__ b3l,
    const float* __restrict__ w3u, const float* __restrict__ b3u,
    const _Float16* __restrict__ pack,
    float* __restrict__ out)
{
    __shared__ __align__(16) _Float16 sm[33792];
    __shared__ float sfl[296];

    const int tid = threadIdx.x;
    const int wave = tid >> 6, lane = tid & 63;
    const int quad = lane >> 4, l16 = lane & 15;
    const int g2b = blockIdx.x * 8;

    // zero activations (23040 fp16 = 11520 u32)
    for (int i = tid; i < 11520; i += 256) ((uint32_t*)sm)[i] = 0u;
    { uint4* d = (uint4*)&sm[D_WQ]; const uint4* s = (const uint4*)(pack + P_D1);
      for (int i = tid; i < 1344; i += 256) d[i] = s[i]; }  // 10752 fp16 = 1344 uint4
    for (int i = tid; i < 32; i += 256) { sfl[SB_B1L + i] = b1l[i]; sfl[SB_B1U + i] = b1u[i]; }
    for (int i = tid; i < 16; i += 256) { sfl[SB_B2L + i] = b2l[i]; sfl[SB_B2U + i] = b2u[i];
                                          sfl[SB_W3U + i] = w3u[i]; }
    for (int i = tid; i < 38; i += 256) sfl[SB_W3L + i] = w3l[i];
    if (tid == 0) { sfl[SB_B3L] = b3l[0]; sfl[SB_B3U] = b3u[0]; }
    __syncthreads();

    // stage xd = [z(64) | lo | up], ea
    for (int i = tid; i < 9216; i += 256) {
        int g = i / 1152, rem = i - g * 1152, node = rem >> 6, f = rem & 63;
        sm[D_XD + (g * 20 + node) * 72 + f] = (_Float16)Zc[(size_t)g2b * 1152 + i];
    }
    for (int i = tid; i < 144; i += 256) {
        int g = i / 18, node = i - g * 18;
        int gb = ((g2b + g) & 8191) * 18 + node;
        sm[D_XD + (g * 20 + node) * 72 + 64] = (_Float16)lo_[gb];
        sm[D_XD + (g * 20 + node) * 72 + 65] = (_Float16)up_[gb];
    }
    for (int i = tid; i < 816; i += 256) {
        int g = i / 102, j = i - g * 102, node = j / 6, c = j - node * 6;
        sm[D_EA + (g * 20 + node) * 16 + c] =
            (_Float16)tea[(size_t)((g2b + g) & 8191) * 102 + j];
    }
    __syncthreads();

    // M-tiles owned: {wave, wave+4, wave+8<10}
    int mts[3] = { wave, wave + 4, wave + 8 };
    const bool has[3] = { true, true, wave < 2 };
    int gN[3], ndN[3], npN[3];
    #pragma unroll
    for (int t = 0; t < 3; t++) {
        const int r16 = mts[t] * 16 + l16;
        gN[t] = r16 / 20; ndN[t] = r16 - gN[t] * 20;
        npN[t] = ndN[t] ? ndN[t] - 1 : 0;
    }

    // ---- dec1: K'=160 (5 Kt), N'=64 (4 Nt) ----
    {
        f32x4 acc[3][4];
        #pragma unroll
        for (int t = 0; t < 3; t++)
            #pragma unroll
            for (int n = 0; n < 4; n++)
                #pragma unroll
                for (int r = 0; r < 4; r++) acc[t][n][r] = 0.f;
        #pragma unroll
        for (int Kt = 0; Kt < 5; Kt++) {
            f16x8 bfr[4];
            #pragma unroll
            for (int nt = 0; nt < 4; nt++)
                bfr[nt] = *(const f16x8*)&sm[D_WQ + (nt * 16 + l16) * 168 + Kt * 32 + quad * 8];
            #pragma unroll
            for (int t = 0; t < 3; t++) if (has[t]) {
                const int aD = D_XD + (gN[t] * 20 + ndN[t]) * 72;
                const int aS = D_XD + (gN[t] * 20 + npN[t]) * 72;
                const int aE = D_EA + (gN[t] * 20 + npN[t]) * 16;
                const int ch = Kt * 4 + quad;
                const int off = ch < 9 ? aD + ch * 8
                              : (ch < 18 ? aS + (ch - 9) * 8 : aE + (ch - 18) * 8);
                f16x8 af = *(const f16x8*)&sm[off];
                #pragma unroll
                for (int nt = 0; nt < 4; nt++)
                    acc[t][nt] = __builtin_amdgcn_mfma_f32_16x16x32_f16(af, bfr[nt], acc[t][nt], 0, 0, 0);
            }
        }
        #pragma unroll
        for (int ntm = 0; ntm < 2; ntm++) {
            const int f = ntm * 16 + l16;
            #pragma unroll
            for (int t = 0; t < 3; t++) if (has[t]) {
                #pragma unroll
                for (int r = 0; r < 4; r++) {
                    const int row = mts[t] * 16 + quad * 4 + r;
                    const int g = row / 20, nd = row - g * 20;
                    if (nd < 18) {
                        const float msg = acc[t][ntm][r]     + sfl[SB_B1L + f];
                        const float u   = acc[t][ntm + 2][r] + sfl[SB_B1U + f];
                        sm[D_H1 + (g * 20 + nd) * 40 + f] =
                            (_Float16)(u + (nd ? lrelu(msg) : 0.f));
                    }
                }
            }
        }
    }
    __syncthreads();
    { uint4* d = (uint4*)&sm[D_WQ]; const uint4* s = (const uint4*)(pack + P_D2);
      for (int i = tid; i < 416; i += 256) d[i] = s[i]; }   // 3328 fp16 = 416 uint4
    __syncthreads();

    // ---- dec2: K'=96 (3 Kt), N'=32 (2 Nt) ----
    {
        f32x4 acc[3][2];
        #pragma unroll
        for (int t = 0; t < 3; t++)
            #pragma unroll
            for (int n = 0; n < 2; n++)
                #pragma unroll
                for (int r = 0; r < 4; r++) acc[t][n][r] = 0.f;
        #pragma unroll
        for (int Kt = 0; Kt < 3; Kt++) {
            f16x8 bfr[2];
            #pragma unroll
            for (int nt = 0; nt < 2; nt++)
                bfr[nt] = *(const f16x8*)&sm[D_WQ + (nt * 16 + l16) * 104 + Kt * 32 + quad * 8];
            #pragma unroll
            for (int t = 0; t < 3; t++) if (has[t]) {
                const int aD = D_H1 + (gN[t] * 20 + ndN[t]) * 40;
                const int aS = D_H1 + (gN[t] * 20 + npN[t]) * 40;
                const int aE = D_EA + (gN[t] * 20 + npN[t]) * 16;
                const int ch = Kt * 4 + quad;
                const int off = ch < 5 ? aD + ch * 8
                              : (ch < 10 ? aS + (ch - 5) * 8 : aE + (ch - 10) * 8);
                f16x8 af = *(const f16x8*)&sm[off];
                #pragma unroll
                for (int nt = 0; nt < 2; nt++)
                    acc[t][nt] = __builtin_amdgcn_mfma_f32_16x16x32_f16(af, bfr[nt], acc[t][nt], 0, 0, 0);
            }
        }
        const int f = l16;
        #pragma unroll
        for (int t = 0; t < 3; t++) if (has[t]) {
            #pragma unroll
            for (int r = 0; r < 4; r++) {
                const int row = mts[t] * 16 + quad * 4 + r;
                const int g = row / 20, nd = row - g * 20;
                if (nd < 18) {
                    const float msg = acc[t][0][r] + sfl[SB_B2L + f];
                    const float u   = acc[t][1][r] + sfl[SB_B2U + f];
                    sm[D_H2 + (g * 20 + nd) * 16 + f] =
                        (_Float16)(u + (nd ? lrelu(msg) : 0.f));
                }
            }
        }
    }
    __syncthreads();

    // ---- dec3 (N=1) + tanh + angle (VALU) ----
    if (tid < 144) {
        const int g = tid / 18, nd = tid - (tid / 18) * 18;
        const _Float16* hn = &sm[D_H2 + (g * 20 + nd) * 16];
        float acc = sfl[SB_B3U];
        #pragma unroll
        for (int c = 0; c < 16; c++) acc += (float)hn[c] * sfl[SB_W3U + c];
        if (nd > 0) {
            const _Float16* hp = &sm[D_H2 + (g * 20 + nd - 1) * 16];
            const _Float16* e  = &sm[D_EA + (g * 20 + nd - 1) * 16];
            float m = sfl[SB_B3L];
            #pragma unroll
            for (int c = 0; c < 16; c++) m += (float)hn[c] * sfl[SB_W3L + c];
            #pragma unroll
            for (int c = 0; c < 16; c++) m += (float)hp[c] * sfl[SB_W3L + 16 + c];
            #pragma unroll
            for (int c = 0; c < 6;  c++) m += (float)e[c]  * sfl[SB_W3L + 32 + c];
            acc += lrelu(m);
        }
        const float hd = tanh_fast(acc);
        const int g2 = g2b + g;
        const int gb = (g2 & 8191) * 18 + nd;
        const float lo = lo_[gb], up = up_[gb];
        const float ang = lo + (up - lo) * (hd + 1.f) * 0.5f;
        sfl[SB_ANG + g * 18 + nd] = ang;
        const size_t abase = (g2 < 8192) ? (size_t)ZSIZE + (size_t)g2 * 18
                                         : (size_t)ZSIZE + AHALF + PHALF + (size_t)(g2 - 8192) * 18;
        out[abase + nd] = ang;
    }
    __syncthreads();

    // ---- FK: sequential 18-joint chain, one thread per graph ----
    if (tid < 8) {
        const int g2 = g2b + tid;
        const int gb = (g2 & 8191) * 18;
        const size_t pbase = (g2 < 8192)
            ? (size_t)ZSIZE + AHALF + (size_t)g2 * 54
            : (size_t)ZSIZE + AHALF + PHALF + AHALF + (size_t)(g2 - 8192) * 54;
        float R[9], p[3];
        for (int j = 0; j < 18; j++) {
            const int m = gb + j;
            const float a0 = ax_[m * 3], a1 = ax_[m * 3 + 1], a2 = ax_[m * 3 + 2];
            const float o0 = off_[m * 3], o1 = off_[m * 3 + 1], o2 = off_[m * 3 + 2];
            const float ang = sfl[SB_ANG + tid * 18 + j];
            float s, c;
            __sincosf(ang, &s, &c);
            const float omc = 1.f - c;
            const float n2 = a0 * a0 + a1 * a1 + a2 * a2;
            float Rl[9];
            Rl[0] = 1.f + omc * (a0 * a0 - n2);
            Rl[1] = -s * a2 + omc * a0 * a1;
            Rl[2] =  s * a1 + omc * a0 * a2;
            Rl[3] =  s * a2 + omc * a1 * a0;
            Rl[4] = 1.f + omc * (a1 * a1 - n2);
            Rl[5] = -s * a0 + omc * a1 * a2;
            Rl[6] = -s * a1 + omc * a2 * a0;
            Rl[7] =  s * a0 + omc * a2 * a1;
            Rl[8] = 1.f + omc * (a2 * a2 - n2);
            if (par_[m] < 0) {
                #pragma unroll
                for (int q = 0; q < 9; q++) R[q] = Rl[q];
                p[0] = o0; p[1] = o1; p[2] = o2;
            } else {
                float Rn[9];
                #pragma unroll
                for (int r = 0; r < 3; r++) {
                    Rn[r * 3 + 0] = R[r * 3] * Rl[0] + R[r * 3 + 1] * Rl[3] + R[r * 3 + 2] * Rl[6];
                    Rn[r * 3 + 1] = R[r * 3] * Rl[1] + R[r * 3 + 1] * Rl[4] + R[r * 3 + 2] * Rl[7];
                    Rn[r * 3 + 2] = R[r * 3] * Rl[2] + R[r * 3 + 1] * Rl[5] + R[r * 3 + 2] * Rl[8];
                }
                const float q0 = p[0] + R[0] * o0 + R[1] * o1 + R[2] * o2;
                const float q1 = p[1] + R[3] * o0 + R[4] * o1 + R[5] * o2;
                const float q2 = p[2] + R[6] * o0 + R[7] * o1 + R[8] * o2;
                #pragma unroll
                for (int q = 0; q < 9; q++) R[q] = Rn[q];
                p[0] = q0; p[1] = q1; p[2] = q2;
            }
            out[pbase + j * 3 + 0] = p[0];
            out[pbase + j * 3 + 1] = p[1];
            out[pbase + j * 3 + 2] = p[2];
        }
    }
}

// ---------------------------------------------------------------------------
extern "C" void kernel_launch(void* const* d_in, const int* in_sizes, int n_in,
                              void* d_out, int out_size, void* d_ws, size_t ws_size,
                              hipStream_t stream)
{
    int i_tw, i_tb, i_d1, i_d2, i_d3;
    if (n_in > 27 && in_sizes[26] == 1088 * 1152) {
        i_tw = 26; i_tb = 27; i_d1 = 28; i_d2 = 32; i_d3 = 36;
    } else {
        i_d1 = 26; i_d2 = 30; i_d3 = 34; i_tw = 38; i_tb = 39;
    }
    auto fp = [&](int i) { return (const float*)d_in[i]; };

    _Float16* Ae   = (_Float16*)((char*)d_ws + WS_AE);
    _Float16* Wt   = (_Float16*)((char*)d_ws + WS_WT);
    _Float16* Pack = (_Float16*)((char*)d_ws + WS_PACK);

    pack_weights<<<dim3(5, 52), 256, 0, stream>>>(
        Pack,
        fp(14), fp(16), fp(18), fp(20), fp(22), fp(24),
        fp(i_d1), fp(i_d1 + 2), fp(i_d2), fp(i_d2 + 2));

    prep_wt<<<dim3(34, 36), dim3(32, 8), 0, stream>>>(fp(i_tw), Wt);

    enc_kernel<<<4096, 256, 0, stream>>>(
        fp(0), fp(1), fp(4), fp(5),
        fp(15), fp(17), fp(19), fp(21), fp(23), fp(25),
        Pack, Ae);

    trans_gemm<<<dim3(128, 9), 256, 0, stream>>>(Ae, Wt, fp(i_tb), (float*)d_out);

    dec_kernel<<<2048, 256, 0, stream>>>(
        (const float*)d_out, fp(7), fp(8), fp(9), fp(10),
        (const int*)d_in[11], fp(12),
        fp(i_d1 + 1), fp(i_d1 + 3), fp(i_d2 + 1), fp(i_d2 + 3),
        fp(i_d3), fp(i_d3 + 1), fp(i_d3 + 2), fp(i_d3 + 3),
        Pack, (float*)d_out);
}